// Round 12
// baseline (285.306 us; speedup 1.0000x reference)
//
#include <hip/hip_runtime.h>
#include <math.h>

#define HH 512
#define WW 512
#define IMG (HH*WW)
#define NIMG_PER 96   // B*C = 32*3
#define NIMG 192      // pred + targ
#define NBIN 256      // max_r
#define EPSV 1e-8f
#define LN2F 0.69314718055994530942f

#define CSTR 264               // padded column count (257 used + 7 zero pad)
#define IMGC (512*CSTR)        // h2 elems per image, row-major [y][kx]
#define NT16 17                // 16-column tiles (kx 0..271, valid <=256)
#define SLOT 575               // per-FFT LDS stride; fsw(511)=574<575
#define SMEM_BYTES 40960       // max(rowfft 36800, colfft 36800+4112)

#define CHUNK 48               // images per pipeline stage (4 stages)
#define NCHUNK 4

typedef float v2f  __attribute__((ext_vector_type(2)));  // packed-fp32 complex
typedef _Float16 h2f __attribute__((ext_vector_type(2)));

__device__ __forceinline__ int drev(int s) {
    return ((s & 7) << 6) | (s & 56) | (s >> 6);
}
__device__ __forceinline__ int fsw(int a) { return a + (a >> 3); }

__device__ __forceinline__ v2f cmul(v2f a, v2f b) {
    return (v2f){a.x, a.x} * b + (v2f){a.y, a.y} * (v2f){-b.y, b.x};
}
__device__ __forceinline__ v2f cni(v2f a) { return (v2f){a.y, -a.x}; }  // * -i

__device__ __forceinline__ v2f h2tof(unsigned int u) {
    h2f h = __builtin_bit_cast(h2f, u);
    return (v2f){(float)h.x, (float)h.y};
}
__device__ __forceinline__ unsigned int ftoh2(v2f v) {
    return __builtin_bit_cast(unsigned int, __builtin_amdgcn_cvt_pkrtz(v.x, v.y));
}

__device__ __forceinline__ void wsync() {
    asm volatile("" ::: "memory");
    __builtin_amdgcn_wave_barrier();
    asm volatile("" ::: "memory");
}

// radix-8 DIF butterfly, negative exponent — packed-2 fp32 ops
__device__ __forceinline__ void bfly8(v2f x[8]) {
    const float R = 0.70710678118654752440f;
    v2f t0=x[0]+x[4], t4=x[0]-x[4];
    v2f t1=x[1]+x[5], t5=x[1]-x[5];
    v2f t2=x[2]+x[6], t6=x[2]-x[6];
    v2f t3=x[3]+x[7], t7=x[3]-x[7];
    v2f u0=t0+t2, u2=t0-t2;
    v2f u1=t1+t3, u3=t1-t3;
    x[0]=u0+u1; x[4]=u0-u1;
    { v2f n3 = cni(u3); x[2]=u2+n3; x[6]=u2-n3; }
    v2f s1 = (v2f){R, R} * ((v2f){t5.x, t5.y} + (v2f){t5.y, -t5.x});
    v2f s2 = cni(t6);
    v2f s3 = (v2f){R, R} * ((v2f){t7.y, -t7.x} - (v2f){t7.x, t7.y});
    v2f v0=t4+s2, v2_=t4-s2;
    v2f v1=s1+s3, v3=s1-s3;
    x[1]=v0+v1; x[5]=v0-v1;
    { v2f m3 = cni(v3); x[3]=v2_+m3; x[7]=v2_-m3; }
}

__device__ __forceinline__ void twiddle7(v2f* x, float ang) {
    const float sn = __sinf(ang), cs = __cosf(ang);
    const v2f w1 = (v2f){cs, sn};
    const v2f w2 = cmul(w1, w1);
    const v2f w3 = cmul(w2, w1);
    const v2f w4 = cmul(w2, w2);
    const v2f w5 = cmul(w2, w3);
    const v2f w6 = cmul(w3, w3);
    const v2f w7 = cmul(w3, w4);
    x[1]=cmul(x[1],w1); x[2]=cmul(x[2],w2); x[3]=cmul(x[3],w3);
    x[4]=cmul(x[4],w4); x[5]=cmul(x[5],w5); x[6]=cmul(x[6],w6);
    x[7]=cmul(x[7],w7);
}

// ---------------------------------------------------------------------------
// rowfft body (identical math to R11): 8 waves = 8 row-pairs of image g,
// zero block barriers, f32 LDS, Hermitian unpack -> coalesced f16 stores.
// ---------------------------------------------------------------------------
__device__ __forceinline__ void rowfft_body(
    char* smem, const float* __restrict__ pred, const float* __restrict__ targ,
    unsigned int* __restrict__ out, int g, int pb)
{
    v2f* sd = (v2f*)smem;
    const int t    = threadIdx.x;
    const int lane = t & 63;
    const int w    = t >> 6;

    const float* img = (g < NIMG_PER) ? (pred + (size_t)g * IMG)
                                      : (targ + (size_t)(g - NIMG_PER) * IMG);
    const float* rowA = img + (size_t)(pb*16 + 2*w) * WW + lane;
    const float* rowB = rowA + WW;

    v2f* p = sd + w * SLOT;
    v2f x[8];
    const int i = lane;

    #pragma unroll
    for (int j = 0; j < 8; ++j)
        x[j] = (v2f){rowA[64*j], rowB[64*j]};
    bfly8(x);
    twiddle7(x, -0.012271846303085130f * (float)i);       // -2pi/512 * i
    {
        v2f* q = p + fsw(i);
        #pragma unroll
        for (int j = 0; j < 8; ++j) q[72*j] = x[j];
    }
    wsync();

    {
        v2f* q = p + 72*(i >> 3) + (i & 7);
        #pragma unroll
        for (int j = 0; j < 8; ++j) x[j] = q[9*j];
        bfly8(x);
        twiddle7(x, -0.098174770424681038f * (float)(i & 7));   // -2pi/64 * i2
        #pragma unroll
        for (int j = 0; j < 8; ++j) q[9*j] = x[j];
    }
    wsync();

    {
        v2f* q = p + 9*i;
        #pragma unroll
        for (int j = 0; j < 8; ++j) x[j] = q[j];
        bfly8(x);
        #pragma unroll
        for (int j = 0; j < 8; ++j) q[j] = x[j];
    }
    wsync();

    unsigned int* dstA = out + (size_t)g * IMGC + (size_t)(pb*16 + 2*w) * CSTR;
    unsigned int* dstB = dstA + CSTR;
    #pragma unroll
    for (int it = 0; it < 5; ++it) {
        const int k = it*64 + lane;
        if (k <= 256) {
            const v2f P = p[fsw(drev(k))];
            const v2f Q = p[fsw(drev((512 - k) & 511))];
            const v2f Fa = (v2f){0.5f, 0.5f} * (P + (v2f){Q.x, -Q.y});
            const v2f Fb = (v2f){0.5f, 0.5f} * ((v2f){P.y, -P.x} + (v2f){Q.y, Q.x});
            dstA[k] = ftoh2(Fa);
            dstB[k] = ftoh2(Fb);
        } else if (k < CSTR) {
            dstA[k] = 0u;
            dstB[k] = 0u;
        }
    }
}

// ---------------------------------------------------------------------------
// colfft body (identical math to R11): 16-column tile of image g, two
// columns per wave, f16 LDS, run-binning, 4 bin replicas.
// ---------------------------------------------------------------------------
__device__ __forceinline__ void colfft_body(
    char* smem, const unsigned int* __restrict__ in,
    float* __restrict__ bins2, int g, int tile)
{
    unsigned int* sd = (unsigned int*)smem;
    float* bs = (float*)(smem + 16*SLOT*sizeof(unsigned int));
    const int t    = threadIdx.x;
    const int lane = t & 63;
    const int w    = t >> 6;

    for (int id = t; id < 4*257; id += 512) bs[id] = 0.0f;

    const int x0 = tile * 16;
    {
        const int y0 = t >> 2;
        const int c  = t & 3;
        int cb = x0 + 4*c;
        if (cb > CSTR - 4) cb = CSTR - 4;
        const uint4* gsrc = (const uint4*)(in + (size_t)g * IMGC
                                              + (size_t)y0 * CSTR + cb);
        unsigned int* d0 = sd + (4*c + 0)*SLOT + fsw(y0);
        unsigned int* d1 = d0 + SLOT;
        unsigned int* d2 = d1 + SLOT;
        unsigned int* d3 = d2 + SLOT;
        #pragma unroll
        for (int it = 0; it < 4; ++it) {
            const uint4 v = gsrc[(size_t)it * 128 * (CSTR/4)];
            d0[144*it] = v.x; d1[144*it] = v.y;
            d2[144*it] = v.z; d3[144*it] = v.w;
        }
    }
    __syncthreads();

    unsigned int* pA = sd + (2*w)     * SLOT;
    unsigned int* pB = sd + (2*w + 1) * SLOT;
    v2f a[8], b[8];
    const int i = lane;

    // ---- stage 1
    {
        unsigned int* qA = pA + fsw(i);
        unsigned int* qB = pB + fsw(i);
        #pragma unroll
        for (int j = 0; j < 8; ++j) { a[j] = h2tof(qA[72*j]); b[j] = h2tof(qB[72*j]); }
        bfly8(a); bfly8(b);
        const float ang = -0.012271846303085130f * (float)i;
        const float sn = __sinf(ang), cs = __cosf(ang);
        const v2f w1 = (v2f){cs, sn};
        const v2f w2 = cmul(w1,w1), w3 = cmul(w2,w1), w4 = cmul(w2,w2);
        const v2f w5 = cmul(w2,w3), w6 = cmul(w3,w3), w7 = cmul(w3,w4);
        a[1]=cmul(a[1],w1); b[1]=cmul(b[1],w1);
        a[2]=cmul(a[2],w2); b[2]=cmul(b[2],w2);
        a[3]=cmul(a[3],w3); b[3]=cmul(b[3],w3);
        a[4]=cmul(a[4],w4); b[4]=cmul(b[4],w4);
        a[5]=cmul(a[5],w5); b[5]=cmul(b[5],w5);
        a[6]=cmul(a[6],w6); b[6]=cmul(b[6],w6);
        a[7]=cmul(a[7],w7); b[7]=cmul(b[7],w7);
        #pragma unroll
        for (int j = 0; j < 8; ++j) { qA[72*j] = ftoh2(a[j]); qB[72*j] = ftoh2(b[j]); }
    }
    wsync();

    // ---- stage 2
    {
        const int off = 72*(i >> 3) + (i & 7);
        unsigned int* qA = pA + off;
        unsigned int* qB = pB + off;
        #pragma unroll
        for (int j = 0; j < 8; ++j) { a[j] = h2tof(qA[9*j]); b[j] = h2tof(qB[9*j]); }
        bfly8(a); bfly8(b);
        const float ang = -0.098174770424681038f * (float)(i & 7);
        const float sn = __sinf(ang), cs = __cosf(ang);
        const v2f w1 = (v2f){cs, sn};
        const v2f w2 = cmul(w1,w1), w3 = cmul(w2,w1), w4 = cmul(w2,w2);
        const v2f w5 = cmul(w2,w3), w6 = cmul(w3,w3), w7 = cmul(w3,w4);
        a[1]=cmul(a[1],w1); b[1]=cmul(b[1],w1);
        a[2]=cmul(a[2],w2); b[2]=cmul(b[2],w2);
        a[3]=cmul(a[3],w3); b[3]=cmul(b[3],w3);
        a[4]=cmul(a[4],w4); b[4]=cmul(b[4],w4);
        a[5]=cmul(a[5],w5); b[5]=cmul(b[5],w5);
        a[6]=cmul(a[6],w6); b[6]=cmul(b[6],w6);
        a[7]=cmul(a[7],w7); b[7]=cmul(b[7],w7);
        #pragma unroll
        for (int j = 0; j < 8; ++j) { qA[9*j] = ftoh2(a[j]); qB[9*j] = ftoh2(b[j]); }
    }
    wsync();

    // ---- stage 3 + writeback
    {
        unsigned int* qA = pA + 9*i;
        unsigned int* qB = pB + 9*i;
        #pragma unroll
        for (int j = 0; j < 8; ++j) { a[j] = h2tof(qA[j]); b[j] = h2tof(qB[j]); }
        bfly8(a); bfly8(b);
        #pragma unroll
        for (int j = 0; j < 8; ++j) { qA[j] = ftoh2(a[j]); qB[j] = ftoh2(b[j]); }
    }
    wsync();

    // ---- binning
    {
        const int h   = lane;
        const int kxA = x0 + 2*w;
        const int kxB = kxA + 1;
        const bool vA = (kxA <= 256), vB = (kxB <= 256);
        const float sA = (kxA == 0 || kxA == 256) ? 0.5f : 1.0f;
        const float sB = (kxB == 256) ? 0.5f : 1.0f;
        const float dxA = (float)((kxA - 256) * (kxA - 256));
        const float dxB = (float)((kxB - 256) * (kxB - 256));
        float* bsw = bs + (w & 3) * 257;
        const int off = fsw(8*(h & 7) + (h >> 3));
        unsigned int* qA = pA + off;
        unsigned int* qB = pB + off;
        float dyf = (float)(8*h - 256);

        float accA = 0.0f, accB = 0.0f;
        int pbA = 1000, pbB = 1000;
        #pragma unroll
        for (int j = 0; j < 8; ++j) {
            const v2f va = h2tof(qA[72*j]);
            const v2f vb = h2tof(qB[72*j]);
            const float la = __log2f(fmaf(va.x, va.x, fmaf(va.y, va.y, EPSV)));
            const float lb = __log2f(fmaf(vb.x, vb.x, fmaf(vb.y, vb.y, EPSV)));
            const int bA = (int)sqrtf(fmaf(dyf, dyf, dxA));
            const int bB = (int)sqrtf(fmaf(dyf, dyf, dxB));
            dyf += 1.0f;
            if (bA != pbA) {
                if (pbA < NBIN && vA) atomicAdd(&bsw[pbA], accA * sA);
                pbA = bA; accA = la;
            } else accA += la;
            if (bB != pbB) {
                if (pbB < NBIN && vB) atomicAdd(&bsw[pbB], accB * sB);
                pbB = bB; accB = lb;
            } else accB += lb;
        }
        if (pbA < NBIN && vA) atomicAdd(&bsw[pbA], accA * sA);
        if (pbB < NBIN && vB) atomicAdd(&bsw[pbB], accB * sB);
    }
    __syncthreads();

    if (t < NBIN) {
        float v = 0.0f;
        #pragma unroll
        for (int r = 0; r < 4; ++r) v += bs[r*257 + t];
        bins2[((size_t)tile * NIMG + g) * NBIN + t] = 2.0f * v;
    }
}

// ---------------------------------------------------------------------------
__global__ __launch_bounds__(512) void rowfft_kernel(
    const float* __restrict__ pred, const float* __restrict__ targ,
    unsigned int* __restrict__ out, int img_base)
{
    extern __shared__ char smem[];
    rowfft_body(smem, pred, targ, out, img_base + blockIdx.y, blockIdx.x);
}

__global__ __launch_bounds__(512) void colfft_kernel(
    const unsigned int* __restrict__ in, float* __restrict__ bins2, int img_base)
{
    extern __shared__ char smem[];
    colfft_body(smem, in, bins2, img_base + blockIdx.y, blockIdx.x);
}

// Combined dispatch: blockIdx.x < 32 -> rowfft on chunk(row_base);
// else -> colfft on chunk(col_base). Independent work, co-scheduled so
// colfft's latency slack is filled by rowfft's HBM streaming.
__global__ __launch_bounds__(512) void combo_kernel(
    const float* __restrict__ pred, const float* __restrict__ targ,
    unsigned int* __restrict__ cbuf, float* __restrict__ bins2,
    int row_base, int col_base)
{
    extern __shared__ char smem[];
    if (blockIdx.x < 32)
        rowfft_body(smem, pred, targ, cbuf, row_base + blockIdx.y, blockIdx.x);
    else
        colfft_body(smem, cbuf, bins2, col_base + blockIdx.y, blockIdx.x - 32);
}

// ---------------------------------------------------------------------------
__global__ __launch_bounds__(256) void reduce_kernel(
    const float* __restrict__ bins2, float* __restrict__ bins)
{
    const int li = blockIdx.x;
    const int t  = threadIdx.x;
    float s = 0.0f;
    #pragma unroll
    for (int tile = 0; tile < NT16; ++tile)
        s += bins2[((size_t)tile * NIMG + li) * NBIN + t];
    bins[(size_t)li * NBIN + t] = s;
}

__global__ __launch_bounds__(256) void counts_kernel(float* __restrict__ cnt)
{
    __shared__ float c[NBIN];
    const int t = threadIdx.x;
    c[t] = 0.0f;
    __syncthreads();

    const int base = blockIdx.x * 4096;
    #pragma unroll
    for (int i = 0; i < 16; ++i) {
        const int id = base + i * 256 + t;
        const int y = id >> 9, xx = id & 511;
        const int dy = y - 256, dx = xx - 256;
        const int b  = (int)sqrtf((float)(dy*dy + dx*dx));
        if (b < NBIN) atomicAdd(&c[b], 1.0f);
    }
    __syncthreads();
    if (c[t] != 0.0f) atomicAdd(&cnt[t], c[t]);
}

__global__ __launch_bounds__(256) void finalize_kernel(
    const float* __restrict__ bins, const float* __restrict__ cnt,
    float* __restrict__ out)
{
    __shared__ float red[256];
    const int t = threadIdx.x;

    float acc = 0.0f;
    for (int id = t; id < NIMG_PER * NBIN; id += 256) {
        const int i = id >> 8;
        const int r = id & 255;
        const float d = fabsf(bins[(size_t)i * NBIN + r]
                            - bins[(size_t)(NIMG_PER + i) * NBIN + r]);
        acc += d / cnt[r];
    }
    red[t] = acc;
    __syncthreads();
    for (int w = 128; w > 0; w >>= 1) {
        if (t < w) red[t] += red[t + w];
        __syncthreads();
    }
    if (t == 0) out[0] = red[0] * (LN2F / (float)(NIMG_PER * NBIN));
}

// ---------------------------------------------------------------------------
extern "C" void kernel_launch(void* const* d_in, const int* in_sizes, int n_in,
                              void* d_out, int out_size, void* d_ws, size_t ws_size,
                              hipStream_t stream)
{
    const float* pred = (const float*)d_in[0];
    const float* targ = (const float*)d_in[1];
    float* out = (float*)d_out;

    char* ws = (char*)d_ws;
    float* cnt   = (float*)ws;                                  // 256
    float* bins  = cnt + NBIN;                                  // 192*256
    float* bins2 = bins + (size_t)NIMG * NBIN;                  // 17*192*256
    const size_t fixed_f = NBIN + (size_t)NIMG*NBIN + (size_t)NT16*NIMG*NBIN;
    const size_t off = (fixed_f*sizeof(float) + 255) & ~(size_t)255;
    unsigned int* cbuf = (unsigned int*)(ws + off);             // f16, 192 imgs

    hipMemsetAsync(cnt, 0, NBIN * sizeof(float), stream);
    counts_kernel<<<dim3(64), dim3(256), 0, stream>>>(cnt);

    // software pipeline: r(0); r(k)||c(k-1) for k=1..3; c(3)
    rowfft_kernel<<<dim3(32, CHUNK), dim3(512), SMEM_BYTES, stream>>>(
        pred, targ, cbuf, 0);
    for (int k = 1; k < NCHUNK; ++k) {
        combo_kernel<<<dim3(32 + NT16, CHUNK), dim3(512), SMEM_BYTES, stream>>>(
            pred, targ, cbuf, bins2, k*CHUNK, (k-1)*CHUNK);
    }
    colfft_kernel<<<dim3(NT16, CHUNK), dim3(512), SMEM_BYTES, stream>>>(
        cbuf, bins2, (NCHUNK-1)*CHUNK);

    reduce_kernel<<<dim3(NIMG), dim3(256), 0, stream>>>(bins2, bins);
    finalize_kernel<<<dim3(1), dim3(256), 0, stream>>>(bins, cnt, out);
}

// Round 13
// 211.316 us; speedup vs baseline: 1.3501x; 1.3501x over previous
//
#include <hip/hip_runtime.h>
#include <math.h>

#define HH 512
#define WW 512
#define IMG (HH*WW)
#define NIMG_PER 96   // B*C = 32*3
#define NIMG 192      // pred + targ
#define NBIN 256      // max_r
#define EPSV 1e-8f
#define LN2F 0.69314718055994530942f

#define CSTR 264               // padded column count (257 used + 7 zero pad)
#define IMGC (512*CSTR)        // h2 elems per image, row-major [y][kx]
#define NT16 17                // 16-column tiles (kx 0..271, valid <=256)
#define SLOT 575               // per-FFT LDS stride; fsw(511)=574<575

typedef float v2f  __attribute__((ext_vector_type(2)));  // packed-fp32 complex
typedef _Float16 h2f __attribute__((ext_vector_type(2)));

__device__ __forceinline__ int drev(int s) {
    return ((s & 7) << 6) | (s & 56) | (s >> 6);
}
__device__ __forceinline__ int fsw(int a) { return a + (a >> 3); }

__device__ __forceinline__ v2f cmul(v2f a, v2f b) {
    return (v2f){a.x, a.x} * b + (v2f){a.y, a.y} * (v2f){-b.y, b.x};
}
__device__ __forceinline__ v2f cni(v2f a) { return (v2f){a.y, -a.x}; }  // * -i

__device__ __forceinline__ v2f h2tof(unsigned int u) {
    h2f h = __builtin_bit_cast(h2f, u);
    return (v2f){(float)h.x, (float)h.y};
}
__device__ __forceinline__ unsigned int ftoh2(v2f v) {
    return __builtin_bit_cast(unsigned int, __builtin_amdgcn_cvt_pkrtz(v.x, v.y));
}

__device__ __forceinline__ void wsync() {
    asm volatile("" ::: "memory");
    __builtin_amdgcn_wave_barrier();
    asm volatile("" ::: "memory");
}

// radix-8 DIF butterfly, negative exponent — packed-2 fp32 ops
__device__ __forceinline__ void bfly8(v2f x[8]) {
    const float R = 0.70710678118654752440f;
    v2f t0=x[0]+x[4], t4=x[0]-x[4];
    v2f t1=x[1]+x[5], t5=x[1]-x[5];
    v2f t2=x[2]+x[6], t6=x[2]-x[6];
    v2f t3=x[3]+x[7], t7=x[3]-x[7];
    v2f u0=t0+t2, u2=t0-t2;
    v2f u1=t1+t3, u3=t1-t3;
    x[0]=u0+u1; x[4]=u0-u1;
    { v2f n3 = cni(u3); x[2]=u2+n3; x[6]=u2-n3; }
    v2f s1 = (v2f){R, R} * ((v2f){t5.x, t5.y} + (v2f){t5.y, -t5.x});
    v2f s2 = cni(t6);
    v2f s3 = (v2f){R, R} * ((v2f){t7.y, -t7.x} - (v2f){t7.x, t7.y});
    v2f v0=t4+s2, v2_=t4-s2;
    v2f v1=s1+s3, v3=s1-s3;
    x[1]=v0+v1; x[5]=v0-v1;
    { v2f m3 = cni(v3); x[3]=v2_+m3; x[7]=v2_-m3; }
}

__device__ __forceinline__ void twiddle7(v2f* x, float ang) {
    const float sn = __sinf(ang), cs = __cosf(ang);
    const v2f w1 = (v2f){cs, sn};
    const v2f w2 = cmul(w1, w1);
    const v2f w3 = cmul(w2, w1);
    const v2f w4 = cmul(w2, w2);
    const v2f w5 = cmul(w2, w3);
    const v2f w6 = cmul(w3, w3);
    const v2f w7 = cmul(w3, w4);
    x[1]=cmul(x[1],w1); x[2]=cmul(x[2],w2); x[3]=cmul(x[3],w3);
    x[4]=cmul(x[4],w4); x[5]=cmul(x[5],w5); x[6]=cmul(x[6],w6);
    x[7]=cmul(x[7],w7);
}

// ---------------------------------------------------------------------------
// Pass A (identical to R11): 512-thr block = 8 waves = 8 row-pairs, zero
// block barriers, f32 LDS, Hermitian unpack -> coalesced f16 [y][kx] stores.
// ---------------------------------------------------------------------------
__global__ __launch_bounds__(512) void rowfft_kernel(
    const float* __restrict__ pred, const float* __restrict__ targ,
    unsigned int* __restrict__ out, int img_base)
{
    __shared__ v2f sd[8*SLOT];
    const int t    = threadIdx.x;
    const int lane = t & 63;
    const int w    = t >> 6;

    const int pb = blockIdx.x;          // rows pb*16 .. pb*16+15
    const int li = blockIdx.y;
    const int g  = img_base + li;
    const float* img = (g < NIMG_PER) ? (pred + (size_t)g * IMG)
                                      : (targ + (size_t)(g - NIMG_PER) * IMG);
    const float* rowA = img + (size_t)(pb*16 + 2*w) * WW + lane;
    const float* rowB = rowA + WW;

    v2f* p = sd + w * SLOT;
    v2f x[8];
    const int i = lane;

    #pragma unroll
    for (int j = 0; j < 8; ++j)
        x[j] = (v2f){rowA[64*j], rowB[64*j]};
    bfly8(x);
    twiddle7(x, -0.012271846303085130f * (float)i);       // -2pi/512 * i
    {
        v2f* q = p + fsw(i);
        #pragma unroll
        for (int j = 0; j < 8; ++j) q[72*j] = x[j];
    }
    wsync();

    {
        v2f* q = p + 72*(i >> 3) + (i & 7);
        #pragma unroll
        for (int j = 0; j < 8; ++j) x[j] = q[9*j];
        bfly8(x);
        twiddle7(x, -0.098174770424681038f * (float)(i & 7));   // -2pi/64 * i2
        #pragma unroll
        for (int j = 0; j < 8; ++j) q[9*j] = x[j];
    }
    wsync();

    {
        v2f* q = p + 9*i;
        #pragma unroll
        for (int j = 0; j < 8; ++j) x[j] = q[j];
        bfly8(x);
        #pragma unroll
        for (int j = 0; j < 8; ++j) q[j] = x[j];
    }
    wsync();

    unsigned int* dstA = out + (size_t)g * IMGC + (size_t)(pb*16 + 2*w) * CSTR;
    unsigned int* dstB = dstA + CSTR;
    #pragma unroll
    for (int it = 0; it < 5; ++it) {
        const int k = it*64 + lane;
        if (k <= 256) {
            const v2f P = p[fsw(drev(k))];
            const v2f Q = p[fsw(drev((512 - k) & 511))];
            const v2f Fa = (v2f){0.5f, 0.5f} * (P + (v2f){Q.x, -Q.y});
            const v2f Fb = (v2f){0.5f, 0.5f} * ((v2f){P.y, -P.x} + (v2f){Q.y, Q.x});
            dstA[k] = ftoh2(Fa);
            dstB[k] = ftoh2(Fb);
        } else if (k < CSTR) {
            dstA[k] = 0u;
            dstB[k] = 0u;
        }
    }
}

// ---------------------------------------------------------------------------
// Pass B: 16-column tile, TWO columns per wave packed as uint2 (colA,colB
// f16-complex) -> every LDS op is ds_*_b64: 64 ds ops/thread vs R11's 128.
// Same math, same binning, 4 bin replicas. Two block barriers.
// ---------------------------------------------------------------------------
__global__ __launch_bounds__(512) void colfft_kernel(
    const unsigned int* __restrict__ in, float* __restrict__ bins2, int img_base)
{
    __shared__ uint2 sd[8*SLOT];       // 8 col-pair planes, 8B/elem
    __shared__ float bs[4*257];        // replica w&3 (waves w, w+4 share)
    const int t    = threadIdx.x;
    const int lane = t & 63;
    const int w    = t >> 6;

    for (int id = t; id < 4*257; id += 512) bs[id] = 0.0f;

    const int li = blockIdx.y;
    const int x0 = blockIdx.x * 16;
    // staging: lane loads uint4 = 4 adjacent f16 columns (= 2 pairs) at one
    // row; writes 2 ds_write_b64. Clamp keeps last tile in-bounds.
    {
        const int y0 = t >> 2;             // 0..127
        const int c  = t & 3;              // column quad 0..3
        int cb = x0 + 4*c;
        if (cb > CSTR - 4) cb = CSTR - 4;
        const uint4* gsrc = (const uint4*)(in + (size_t)li * IMGC
                                              + (size_t)y0 * CSTR + cb);
        uint2* d0 = sd + (2*c + 0)*SLOT + fsw(y0);
        uint2* d1 = d0 + SLOT;
        #pragma unroll
        for (int it = 0; it < 4; ++it) {   // y = y0+128it; fsw -> +144it
            const uint4 v = gsrc[(size_t)it * 128 * (CSTR/4)];
            d0[144*it] = make_uint2(v.x, v.y);
            d1[144*it] = make_uint2(v.z, v.w);
        }
    }
    __syncthreads();

    // wave w owns pair plane w = columns x0+2w, x0+2w+1
    uint2* p = sd + w * SLOT;
    v2f a[8], b[8];
    const int i = lane;

    // ---- stage 1
    {
        uint2* q = p + fsw(i);
        #pragma unroll
        for (int j = 0; j < 8; ++j) {
            const uint2 u = q[72*j];
            a[j] = h2tof(u.x); b[j] = h2tof(u.y);
        }
        bfly8(a); bfly8(b);
        const float ang = -0.012271846303085130f * (float)i;
        const float sn = __sinf(ang), cs = __cosf(ang);
        const v2f w1 = (v2f){cs, sn};
        const v2f w2 = cmul(w1,w1), w3 = cmul(w2,w1), w4 = cmul(w2,w2);
        const v2f w5 = cmul(w2,w3), w6 = cmul(w3,w3), w7 = cmul(w3,w4);
        a[1]=cmul(a[1],w1); b[1]=cmul(b[1],w1);
        a[2]=cmul(a[2],w2); b[2]=cmul(b[2],w2);
        a[3]=cmul(a[3],w3); b[3]=cmul(b[3],w3);
        a[4]=cmul(a[4],w4); b[4]=cmul(b[4],w4);
        a[5]=cmul(a[5],w5); b[5]=cmul(b[5],w5);
        a[6]=cmul(a[6],w6); b[6]=cmul(b[6],w6);
        a[7]=cmul(a[7],w7); b[7]=cmul(b[7],w7);
        #pragma unroll
        for (int j = 0; j < 8; ++j) q[72*j] = make_uint2(ftoh2(a[j]), ftoh2(b[j]));
    }
    wsync();

    // ---- stage 2
    {
        uint2* q = p + 72*(i >> 3) + (i & 7);
        #pragma unroll
        for (int j = 0; j < 8; ++j) {
            const uint2 u = q[9*j];
            a[j] = h2tof(u.x); b[j] = h2tof(u.y);
        }
        bfly8(a); bfly8(b);
        const float ang = -0.098174770424681038f * (float)(i & 7);
        const float sn = __sinf(ang), cs = __cosf(ang);
        const v2f w1 = (v2f){cs, sn};
        const v2f w2 = cmul(w1,w1), w3 = cmul(w2,w1), w4 = cmul(w2,w2);
        const v2f w5 = cmul(w2,w3), w6 = cmul(w3,w3), w7 = cmul(w3,w4);
        a[1]=cmul(a[1],w1); b[1]=cmul(b[1],w1);
        a[2]=cmul(a[2],w2); b[2]=cmul(b[2],w2);
        a[3]=cmul(a[3],w3); b[3]=cmul(b[3],w3);
        a[4]=cmul(a[4],w4); b[4]=cmul(b[4],w4);
        a[5]=cmul(a[5],w5); b[5]=cmul(b[5],w5);
        a[6]=cmul(a[6],w6); b[6]=cmul(b[6],w6);
        a[7]=cmul(a[7],w7); b[7]=cmul(b[7],w7);
        #pragma unroll
        for (int j = 0; j < 8; ++j) q[9*j] = make_uint2(ftoh2(a[j]), ftoh2(b[j]));
    }
    wsync();

    // ---- stage 3 + writeback (enables consecutive-ky regather)
    {
        uint2* q = p + 9*i;
        #pragma unroll
        for (int j = 0; j < 8; ++j) {
            const uint2 u = q[j];
            a[j] = h2tof(u.x); b[j] = h2tof(u.y);
        }
        bfly8(a); bfly8(b);
        #pragma unroll
        for (int j = 0; j < 8; ++j) q[j] = make_uint2(ftoh2(a[j]), ftoh2(b[j]));
    }
    wsync();

    // ---- binning: lane h owns ky = 8h..8h+7 of both columns; run-accumulate,
    // LDS atomic per bin change.
    {
        const int h   = lane;
        const int kxA = x0 + 2*w;
        const int kxB = kxA + 1;
        const bool vA = (kxA <= 256), vB = (kxB <= 256);
        const float sA = (kxA == 0 || kxA == 256) ? 0.5f : 1.0f;
        const float sB = (kxB == 256) ? 0.5f : 1.0f;
        const float dxA = (float)((kxA - 256) * (kxA - 256));
        const float dxB = (float)((kxB - 256) * (kxB - 256));
        float* bsw = bs + (w & 3) * 257;
        uint2* q = p + fsw(8*(h & 7) + (h >> 3));
        float dyf = (float)(8*h - 256);

        float accA = 0.0f, accB = 0.0f;
        int pbA = 1000, pbB = 1000;
        #pragma unroll
        for (int j = 0; j < 8; ++j) {
            const uint2 u = q[72*j];
            const v2f va = h2tof(u.x);
            const v2f vb = h2tof(u.y);
            const float la = __log2f(fmaf(va.x, va.x, fmaf(va.y, va.y, EPSV)));
            const float lb = __log2f(fmaf(vb.x, vb.x, fmaf(vb.y, vb.y, EPSV)));
            const int bA = (int)sqrtf(fmaf(dyf, dyf, dxA));
            const int bB = (int)sqrtf(fmaf(dyf, dyf, dxB));
            dyf += 1.0f;
            if (bA != pbA) {
                if (pbA < NBIN && vA) atomicAdd(&bsw[pbA], accA * sA);
                pbA = bA; accA = la;
            } else accA += la;
            if (bB != pbB) {
                if (pbB < NBIN && vB) atomicAdd(&bsw[pbB], accB * sB);
                pbB = bB; accB = lb;
            } else accB += lb;
        }
        if (pbA < NBIN && vA) atomicAdd(&bsw[pbA], accA * sA);
        if (pbB < NBIN && vB) atomicAdd(&bsw[pbB], accB * sB);
    }
    __syncthreads();

    if (t < NBIN) {
        float v = 0.0f;
        #pragma unroll
        for (int r = 0; r < 4; ++r) v += bs[r*257 + t];
        bins2[((size_t)blockIdx.x * NIMG + (img_base + li)) * NBIN + t] = 2.0f * v;
    }
}

// ---------------------------------------------------------------------------
__global__ __launch_bounds__(256) void reduce_kernel(
    const float* __restrict__ bins2, float* __restrict__ bins)
{
    const int li = blockIdx.x;
    const int t  = threadIdx.x;
    float s = 0.0f;
    #pragma unroll
    for (int tile = 0; tile < NT16; ++tile)
        s += bins2[((size_t)tile * NIMG + li) * NBIN + t];
    bins[(size_t)li * NBIN + t] = s;
}

// ---------------------------------------------------------------------------
__global__ __launch_bounds__(256) void counts_kernel(float* __restrict__ cnt)
{
    __shared__ float c[NBIN];
    const int t = threadIdx.x;
    c[t] = 0.0f;
    __syncthreads();

    const int base = blockIdx.x * 4096;
    #pragma unroll
    for (int i = 0; i < 16; ++i) {
        const int id = base + i * 256 + t;
        const int y = id >> 9, xx = id & 511;
        const int dy = y - 256, dx = xx - 256;
        const int b  = (int)sqrtf((float)(dy*dy + dx*dx));
        if (b < NBIN) atomicAdd(&c[b], 1.0f);
    }
    __syncthreads();
    if (c[t] != 0.0f) atomicAdd(&cnt[t], c[t]);
}

// ---------------------------------------------------------------------------
__global__ __launch_bounds__(256) void finalize_kernel(
    const float* __restrict__ bins, const float* __restrict__ cnt,
    float* __restrict__ out)
{
    __shared__ float red[256];
    const int t = threadIdx.x;

    float acc = 0.0f;
    for (int id = t; id < NIMG_PER * NBIN; id += 256) {
        const int i = id >> 8;
        const int r = id & 255;
        const float d = fabsf(bins[(size_t)i * NBIN + r]
                            - bins[(size_t)(NIMG_PER + i) * NBIN + r]);
        acc += d / cnt[r];
    }
    red[t] = acc;
    __syncthreads();
    for (int w = 128; w > 0; w >>= 1) {
        if (t < w) red[t] += red[t + w];
        __syncthreads();
    }
    if (t == 0) out[0] = red[0] * (LN2F / (float)(NIMG_PER * NBIN));
}

// ---------------------------------------------------------------------------
extern "C" void kernel_launch(void* const* d_in, const int* in_sizes, int n_in,
                              void* d_out, int out_size, void* d_ws, size_t ws_size,
                              hipStream_t stream)
{
    const float* pred = (const float*)d_in[0];
    const float* targ = (const float*)d_in[1];
    float* out = (float*)d_out;

    char* ws = (char*)d_ws;
    float* cnt   = (float*)ws;                                  // 256
    float* bins  = cnt + NBIN;                                  // 192*256
    float* bins2 = bins + (size_t)NIMG * NBIN;                  // 17*192*256
    const size_t fixed_f = NBIN + (size_t)NIMG*NBIN + (size_t)NT16*NIMG*NBIN;
    const size_t off = (fixed_f*sizeof(float) + 255) & ~(size_t)255;
    unsigned int* cbuf = (unsigned int*)(ws + off);             // f16 complex

    const size_t per_img = (size_t)IMGC * sizeof(unsigned int); // ~528 KiB
    size_t avail = (ws_size > off) ? (ws_size - off) : 0;
    int chunk = (int)(avail / per_img);
    if (chunk > NIMG) chunk = NIMG;
    if (chunk < 1) chunk = 1;

    hipMemsetAsync(cnt, 0, NBIN * sizeof(float), stream);
    counts_kernel<<<dim3(64), dim3(256), 0, stream>>>(cnt);

    for (int base = 0; base < NIMG; base += chunk) {
        const int n = (NIMG - base < chunk) ? (NIMG - base) : chunk;
        dim3 gA(HH / 16, n), gB(NT16, n);
        rowfft_kernel<<<gA, dim3(512), 0, stream>>>(pred, targ, cbuf, base);
        colfft_kernel<<<gB, dim3(512), 0, stream>>>(cbuf, bins2, base);
    }

    reduce_kernel<<<dim3(NIMG), dim3(256), 0, stream>>>(bins2, bins);
    finalize_kernel<<<dim3(1), dim3(256), 0, stream>>>(bins, cnt, out);
}

// Round 14
// 208.781 us; speedup vs baseline: 1.3665x; 1.0121x over previous
//
#include <hip/hip_runtime.h>
#include <math.h>

#define HH 512
#define WW 512
#define IMG (HH*WW)
#define NIMG_PER 96   // B*C = 32*3
#define NIMG 192      // pred + targ
#define NBIN 256      // max_r
#define EPSV 1e-8f
#define LN2F 0.69314718055994530942f

#define CSTR 264               // padded column count (257 used + 7 zero pad)
#define IMGC (512*CSTR)        // h2 elems per image, row-major [y][kx]
#define NT16 17                // 16-column tiles (kx 0..271, valid <=256)
#define SLOT 575               // per-FFT LDS stride; fsw(511)=574<575

typedef float v2f  __attribute__((ext_vector_type(2)));  // packed-fp32 complex
typedef _Float16 h2f __attribute__((ext_vector_type(2)));

__device__ __forceinline__ int drev(int s) {
    return ((s & 7) << 6) | (s & 56) | (s >> 6);
}
__device__ __forceinline__ int fsw(int a) { return a + (a >> 3); }

__device__ __forceinline__ v2f cmul(v2f a, v2f b) {
    return (v2f){a.x, a.x} * b + (v2f){a.y, a.y} * (v2f){-b.y, b.x};
}
__device__ __forceinline__ v2f cni(v2f a) { return (v2f){a.y, -a.x}; }  // * -i

__device__ __forceinline__ v2f h2tof(unsigned int u) {
    h2f h = __builtin_bit_cast(h2f, u);
    return (v2f){(float)h.x, (float)h.y};
}
__device__ __forceinline__ unsigned int ftoh2(v2f v) {
    return __builtin_bit_cast(unsigned int, __builtin_amdgcn_cvt_pkrtz(v.x, v.y));
}

__device__ __forceinline__ void wsync() {
    asm volatile("" ::: "memory");
    __builtin_amdgcn_wave_barrier();
    asm volatile("" ::: "memory");
}

// radix-8 DIF butterfly, negative exponent — packed-2 fp32 ops
__device__ __forceinline__ void bfly8(v2f x[8]) {
    const float R = 0.70710678118654752440f;
    v2f t0=x[0]+x[4], t4=x[0]-x[4];
    v2f t1=x[1]+x[5], t5=x[1]-x[5];
    v2f t2=x[2]+x[6], t6=x[2]-x[6];
    v2f t3=x[3]+x[7], t7=x[3]-x[7];
    v2f u0=t0+t2, u2=t0-t2;
    v2f u1=t1+t3, u3=t1-t3;
    x[0]=u0+u1; x[4]=u0-u1;
    { v2f n3 = cni(u3); x[2]=u2+n3; x[6]=u2-n3; }
    v2f s1 = (v2f){R, R} * ((v2f){t5.x, t5.y} + (v2f){t5.y, -t5.x});
    v2f s2 = cni(t6);
    v2f s3 = (v2f){R, R} * ((v2f){t7.y, -t7.x} - (v2f){t7.x, t7.y});
    v2f v0=t4+s2, v2_=t4-s2;
    v2f v1=s1+s3, v3=s1-s3;
    x[1]=v0+v1; x[5]=v0-v1;
    { v2f m3 = cni(v3); x[3]=v2_+m3; x[7]=v2_-m3; }
}

__device__ __forceinline__ void twiddle7(v2f* x, float ang) {
    const float sn = __sinf(ang), cs = __cosf(ang);
    const v2f w1 = (v2f){cs, sn};
    const v2f w2 = cmul(w1, w1);
    const v2f w3 = cmul(w2, w1);
    const v2f w4 = cmul(w2, w2);
    const v2f w5 = cmul(w2, w3);
    const v2f w6 = cmul(w3, w3);
    const v2f w7 = cmul(w3, w4);
    x[1]=cmul(x[1],w1); x[2]=cmul(x[2],w2); x[3]=cmul(x[3],w3);
    x[4]=cmul(x[4],w4); x[5]=cmul(x[5],w5); x[6]=cmul(x[6],w6);
    x[7]=cmul(x[7],w7);
}

// ---------------------------------------------------------------------------
// Pass A (unchanged — runs at ~94% of achievable HBM): 8 waves = 8 row-pairs,
// zero block barriers, f32 LDS, Hermitian unpack -> coalesced f16 stores.
// ---------------------------------------------------------------------------
__global__ __launch_bounds__(512) void rowfft_kernel(
    const float* __restrict__ pred, const float* __restrict__ targ,
    unsigned int* __restrict__ out, int img_base)
{
    __shared__ v2f sd[8*SLOT];
    const int t    = threadIdx.x;
    const int lane = t & 63;
    const int w    = t >> 6;

    const int pb = blockIdx.x;          // rows pb*16 .. pb*16+15
    const int li = blockIdx.y;
    const int g  = img_base + li;
    const float* img = (g < NIMG_PER) ? (pred + (size_t)g * IMG)
                                      : (targ + (size_t)(g - NIMG_PER) * IMG);
    const float* rowA = img + (size_t)(pb*16 + 2*w) * WW + lane;
    const float* rowB = rowA + WW;

    v2f* p = sd + w * SLOT;
    v2f x[8];
    const int i = lane;

    #pragma unroll
    for (int j = 0; j < 8; ++j)
        x[j] = (v2f){rowA[64*j], rowB[64*j]};
    bfly8(x);
    twiddle7(x, -0.012271846303085130f * (float)i);       // -2pi/512 * i
    {
        v2f* q = p + fsw(i);
        #pragma unroll
        for (int j = 0; j < 8; ++j) q[72*j] = x[j];
    }
    wsync();

    {
        v2f* q = p + 72*(i >> 3) + (i & 7);
        #pragma unroll
        for (int j = 0; j < 8; ++j) x[j] = q[9*j];
        bfly8(x);
        twiddle7(x, -0.098174770424681038f * (float)(i & 7));   // -2pi/64 * i2
        #pragma unroll
        for (int j = 0; j < 8; ++j) q[9*j] = x[j];
    }
    wsync();

    {
        v2f* q = p + 9*i;
        #pragma unroll
        for (int j = 0; j < 8; ++j) x[j] = q[j];
        bfly8(x);
        #pragma unroll
        for (int j = 0; j < 8; ++j) q[j] = x[j];
    }
    wsync();

    unsigned int* dstA = out + (size_t)g * IMGC + (size_t)(pb*16 + 2*w) * CSTR;
    unsigned int* dstB = dstA + CSTR;
    #pragma unroll
    for (int it = 0; it < 5; ++it) {
        const int k = it*64 + lane;
        if (k <= 256) {
            const v2f P = p[fsw(drev(k))];
            const v2f Q = p[fsw(drev((512 - k) & 511))];
            const v2f Fa = (v2f){0.5f, 0.5f} * (P + (v2f){Q.x, -Q.y});
            const v2f Fb = (v2f){0.5f, 0.5f} * ((v2f){P.y, -P.x} + (v2f){Q.y, Q.x});
            dstA[k] = ftoh2(Fa);
            dstB[k] = ftoh2(Fb);
        } else if (k < CSTR) {
            dstA[k] = 0u;
            dstB[k] = 0u;
        }
    }
}

// ---------------------------------------------------------------------------
// Pass B — CODE-SIZE DIET (same math/layout as R13): stages 1-2 in a rolled
// loop (one body), binning rolled. Target <8 KB of code (I$ = 32 KB/CU).
// ---------------------------------------------------------------------------
__global__ __launch_bounds__(512) void colfft_kernel(
    const unsigned int* __restrict__ in, float* __restrict__ bins2, int img_base)
{
    __shared__ uint2 sd[8*SLOT];       // 8 col-pair planes, 8B/elem
    __shared__ float bs[4*257];        // replica w&3 (waves w, w+4 share)
    const int t    = threadIdx.x;
    const int lane = t & 63;
    const int w    = t >> 6;

    for (int id = t; id < 4*257; id += 512) bs[id] = 0.0f;

    const int li = blockIdx.y;
    const int x0 = blockIdx.x * 16;
    // staging: lane loads uint4 = 4 adjacent f16 columns (= 2 pairs) per row
    {
        const int y0 = t >> 2;             // 0..127
        const int c  = t & 3;              // column quad 0..3
        int cb = x0 + 4*c;
        if (cb > CSTR - 4) cb = CSTR - 4;
        const uint4* gsrc = (const uint4*)(in + (size_t)li * IMGC
                                              + (size_t)y0 * CSTR + cb);
        uint2* d0 = sd + (2*c + 0)*SLOT + fsw(y0);
        uint2* d1 = d0 + SLOT;
        #pragma unroll
        for (int it = 0; it < 4; ++it) {   // y = y0+128it; fsw -> +144it
            const uint4 v = gsrc[(size_t)it * 128 * (CSTR/4)];
            d0[144*it] = make_uint2(v.x, v.y);
            d1[144*it] = make_uint2(v.z, v.w);
        }
    }
    __syncthreads();

    // wave w owns pair plane w = columns x0+2w, x0+2w+1
    uint2* p = sd + w * SLOT;
    const int i = lane;

    // ---- stages 1 and 2: ONE rolled loop (code shared)
    #pragma unroll 1
    for (int s = 0; s < 2; ++s) {
        uint2* q;
        int stride;
        float ang;
        if (s == 0) {
            q = p + fsw(i); stride = 72;
            ang = -0.012271846303085130f * (float)i;          // -2pi/512 * i
        } else {
            q = p + 72*(i >> 3) + (i & 7); stride = 9;
            ang = -0.098174770424681038f * (float)(i & 7);    // -2pi/64 * i2
        }
        v2f a[8], b[8];
        {
            uint2* r = q;
            #pragma unroll
            for (int j = 0; j < 8; ++j) {
                const uint2 u = *r; r += stride;
                a[j] = h2tof(u.x); b[j] = h2tof(u.y);
            }
        }
        bfly8(a); bfly8(b);
        {
            const float sn = __sinf(ang), cs = __cosf(ang);
            const v2f w1 = (v2f){cs, sn};
            const v2f w2 = cmul(w1,w1), w3 = cmul(w2,w1), w4 = cmul(w2,w2);
            const v2f w5 = cmul(w2,w3), w6 = cmul(w3,w3), w7 = cmul(w3,w4);
            a[1]=cmul(a[1],w1); b[1]=cmul(b[1],w1);
            a[2]=cmul(a[2],w2); b[2]=cmul(b[2],w2);
            a[3]=cmul(a[3],w3); b[3]=cmul(b[3],w3);
            a[4]=cmul(a[4],w4); b[4]=cmul(b[4],w4);
            a[5]=cmul(a[5],w5); b[5]=cmul(b[5],w5);
            a[6]=cmul(a[6],w6); b[6]=cmul(b[6],w6);
            a[7]=cmul(a[7],w7); b[7]=cmul(b[7],w7);
        }
        {
            uint2* r = q;
            #pragma unroll
            for (int j = 0; j < 8; ++j) {
                *r = make_uint2(ftoh2(a[j]), ftoh2(b[j])); r += stride;
            }
        }
        wsync();
    }

    // ---- stage 3 + writeback (no twiddle)
    {
        uint2* q = p + 9*i;
        v2f a[8], b[8];
        #pragma unroll
        for (int j = 0; j < 8; ++j) {
            const uint2 u = q[j];
            a[j] = h2tof(u.x); b[j] = h2tof(u.y);
        }
        bfly8(a); bfly8(b);
        #pragma unroll
        for (int j = 0; j < 8; ++j) q[j] = make_uint2(ftoh2(a[j]), ftoh2(b[j]));
    }
    wsync();

    // ---- binning (rolled): lane h owns ky = 8h..8h+7 of both columns;
    // run-accumulate, LDS atomic per bin change.
    {
        const int h   = lane;
        const int kxA = x0 + 2*w;
        const int kxB = kxA + 1;
        const bool vA = (kxA <= 256), vB = (kxB <= 256);
        const float sA = (kxA == 0 || kxA == 256) ? 0.5f : 1.0f;
        const float sB = (kxB == 256) ? 0.5f : 1.0f;
        const float dxA = (float)((kxA - 256) * (kxA - 256));
        const float dxB = (float)((kxB - 256) * (kxB - 256));
        float* bsw = bs + (w & 3) * 257;
        uint2* q = p + fsw(8*(h & 7) + (h >> 3));
        float dyf = (float)(8*h - 256);

        float accA = 0.0f, accB = 0.0f;
        int pbA = 1000, pbB = 1000;
        #pragma unroll 1
        for (int j = 0; j < 8; ++j) {
            const uint2 u = *q; q += 72;
            const v2f va = h2tof(u.x);
            const v2f vb = h2tof(u.y);
            const float la = __log2f(fmaf(va.x, va.x, fmaf(va.y, va.y, EPSV)));
            const float lb = __log2f(fmaf(vb.x, vb.x, fmaf(vb.y, vb.y, EPSV)));
            const int bA = (int)sqrtf(fmaf(dyf, dyf, dxA));
            const int bB = (int)sqrtf(fmaf(dyf, dyf, dxB));
            dyf += 1.0f;
            if (bA != pbA) {
                if (pbA < NBIN && vA) atomicAdd(&bsw[pbA], accA * sA);
                pbA = bA; accA = la;
            } else accA += la;
            if (bB != pbB) {
                if (pbB < NBIN && vB) atomicAdd(&bsw[pbB], accB * sB);
                pbB = bB; accB = lb;
            } else accB += lb;
        }
        if (pbA < NBIN && vA) atomicAdd(&bsw[pbA], accA * sA);
        if (pbB < NBIN && vB) atomicAdd(&bsw[pbB], accB * sB);
    }
    __syncthreads();

    if (t < NBIN) {
        float v = 0.0f;
        #pragma unroll
        for (int r = 0; r < 4; ++r) v += bs[r*257 + t];
        bins2[((size_t)blockIdx.x * NIMG + (img_base + li)) * NBIN + t] = 2.0f * v;
    }
}

// ---------------------------------------------------------------------------
__global__ __launch_bounds__(256) void reduce_kernel(
    const float* __restrict__ bins2, float* __restrict__ bins)
{
    const int li = blockIdx.x;
    const int t  = threadIdx.x;
    float s = 0.0f;
    #pragma unroll
    for (int tile = 0; tile < NT16; ++tile)
        s += bins2[((size_t)tile * NIMG + li) * NBIN + t];
    bins[(size_t)li * NBIN + t] = s;
}

// ---------------------------------------------------------------------------
__global__ __launch_bounds__(256) void counts_kernel(float* __restrict__ cnt)
{
    __shared__ float c[NBIN];
    const int t = threadIdx.x;
    c[t] = 0.0f;
    __syncthreads();

    const int base = blockIdx.x * 4096;
    #pragma unroll
    for (int i = 0; i < 16; ++i) {
        const int id = base + i * 256 + t;
        const int y = id >> 9, xx = id & 511;
        const int dy = y - 256, dx = xx - 256;
        const int b  = (int)sqrtf((float)(dy*dy + dx*dx));
        if (b < NBIN) atomicAdd(&c[b], 1.0f);
    }
    __syncthreads();
    if (c[t] != 0.0f) atomicAdd(&cnt[t], c[t]);
}

// ---------------------------------------------------------------------------
__global__ __launch_bounds__(256) void finalize_kernel(
    const float* __restrict__ bins, const float* __restrict__ cnt,
    float* __restrict__ out)
{
    __shared__ float red[256];
    const int t = threadIdx.x;

    float acc = 0.0f;
    for (int id = t; id < NIMG_PER * NBIN; id += 256) {
        const int i = id >> 8;
        const int r = id & 255;
        const float d = fabsf(bins[(size_t)i * NBIN + r]
                            - bins[(size_t)(NIMG_PER + i) * NBIN + r]);
        acc += d / cnt[r];
    }
    red[t] = acc;
    __syncthreads();
    for (int w = 128; w > 0; w >>= 1) {
        if (t < w) red[t] += red[t + w];
        __syncthreads();
    }
    if (t == 0) out[0] = red[0] * (LN2F / (float)(NIMG_PER * NBIN));
}

// ---------------------------------------------------------------------------
extern "C" void kernel_launch(void* const* d_in, const int* in_sizes, int n_in,
                              void* d_out, int out_size, void* d_ws, size_t ws_size,
                              hipStream_t stream)
{
    const float* pred = (const float*)d_in[0];
    const float* targ = (const float*)d_in[1];
    float* out = (float*)d_out;

    char* ws = (char*)d_ws;
    float* cnt   = (float*)ws;                                  // 256
    float* bins  = cnt + NBIN;                                  // 192*256
    float* bins2 = bins + (size_t)NIMG * NBIN;                  // 17*192*256
    const size_t fixed_f = NBIN + (size_t)NIMG*NBIN + (size_t)NT16*NIMG*NBIN;
    const size_t off = (fixed_f*sizeof(float) + 255) & ~(size_t)255;
    unsigned int* cbuf = (unsigned int*)(ws + off);             // f16 complex

    const size_t per_img = (size_t)IMGC * sizeof(unsigned int); // ~528 KiB
    size_t avail = (ws_size > off) ? (ws_size - off) : 0;
    int chunk = (int)(avail / per_img);
    if (chunk > NIMG) chunk = NIMG;
    if (chunk < 1) chunk = 1;

    hipMemsetAsync(cnt, 0, NBIN * sizeof(float), stream);
    counts_kernel<<<dim3(64), dim3(256), 0, stream>>>(cnt);

    for (int base = 0; base < NIMG; base += chunk) {
        const int n = (NIMG - base < chunk) ? (NIMG - base) : chunk;
        dim3 gA(HH / 16, n), gB(NT16, n);
        rowfft_kernel<<<gA, dim3(512), 0, stream>>>(pred, targ, cbuf, base);
        colfft_kernel<<<gB, dim3(512), 0, stream>>>(cbuf, bins2, base);
    }

    reduce_kernel<<<dim3(NIMG), dim3(256), 0, stream>>>(bins2, bins);
    finalize_kernel<<<dim3(1), dim3(256), 0, stream>>>(bins, cnt, out);
}